// Round 18
// baseline (275.041 us; speedup 1.0000x reference)
//
#include <hip/hip_runtime.h>
#include <math.h>

#define HH 512
#define WW 512
#define HW (HH * WW)

#define T_OFF_U 36864             // ushort offset of bf16 tile T (A region = 64co*9*64ci)
#define F_OFF_U 58624             // ushort offset of fp32 chunk buf F (T = 10*34*64 = 21760)
#define LDS_BYTES (F_OFF_U * 2 + 25600)   // 117248 + 25600 = 142848 <= 160 KiB pool

typedef short bf16x8 __attribute__((ext_vector_type(8)));
typedef float f32x4  __attribute__((ext_vector_type(4)));
typedef float f32x16 __attribute__((ext_vector_type(16)));

__device__ __forceinline__ ushort f2bf(float f) {
    union { float f; uint u; } c; c.f = f;
    uint u = c.u;
    return (ushort)((u + 0x7fffu + ((u >> 16) & 1u)) >> 16);
}

__device__ __forceinline__ uint cvtpk(float a, float b) {
    uint r;
    asm("v_cvt_pk_bf16_f32 %0, %1, %2" : "=v"(r) : "v"(a), "v"(b));
    return r;
}

// ---------------- kernel 1: styles ----------------
__global__ void k_styles(const float* __restrict__ wsv, const float* __restrict__ aw,
                         const float* __restrict__ ab, float* __restrict__ styles) {
    int bid = blockIdx.x;
    int b = bid >> 6, ci = bid & 63;
    int l = threadIdx.x;
    const float* wrow = wsv + b * 512;
    const float* arow = aw + ci * 512;
    float s = 0.f;
    #pragma unroll
    for (int j = 0; j < 8; ++j)
        s += wrow[l + 64 * j] * arow[l + 64 * j];
    #pragma unroll
    for (int off = 32; off; off >>= 1)
        s += __shfl_xor(s, off, 64);
    if (l == 0)
        styles[b * 64 + ci] = s * 0.044194173824159216f + ab[ci];
}

// ------------- kernel 2: modulate+demodulate -> bf16 [b][co][off 9][ci 64] -------------
// ci-group (ci>>3) stored XORed with (co&7): conflict-free weight ds_reads after a
// purely LINEAR global_load_lds stage (swizzle baked at write time). (R8/R10-proven)
__global__ void k_wmod(const float* __restrict__ cw, const float* __restrict__ styles,
                       ushort* __restrict__ wb) {
    int b = blockIdx.x >> 6, co = blockIdx.x & 63;
    int ci = threadIdx.x;
    float st = styles[b * 64 + ci];
    const float* wp = cw + (co * 64 + ci) * 9;
    float wv[9];
    float ss = 0.f;
    #pragma unroll
    for (int k = 0; k < 9; ++k) { wv[k] = wp[k] * st; ss += wv[k] * wv[k]; }
    #pragma unroll
    for (int off = 32; off; off >>= 1)
        ss += __shfl_xor(ss, off, 64);
    float dm = 1.0f / sqrtf(ss + 1e-8f);
    int cisw = ((((ci >> 3) ^ co) & 7) << 3) | (ci & 7);
    #pragma unroll
    for (int k = 0; k < 9; ++k)
        wb[((size_t)(b * 64 + co) * 9 + k) * 64 + cisw] = f2bf(wv[k] * dm);
}

// ------------- kernel 3: FUSED persistent MFMA conv (no xpose pass) -------------
// 256 blocks (1/CU), 256 threads (4 waves). Block = (b, 8-row band); 16 col-tiles
// of 8 rows x 32 cols.
// Staging per tile (R5-proven code): 4 chunks of 16 ci planes: x fp32 ->
// global_load_lds -> F [16ci][10r][40c] fp32 (25 KB) -> in-LDS cvt/transpose
// (xpose's inner loop) -> bf16 tile T [10r][34c][64ci], ci-group swizzled
// (2cc+cs)^(lcol&7) == the R15 read swizzle (2kb+hl)^(lcol&7). MFMA + epilogue
// carried verbatim from R15. Saves the entire 85us xpose kernel + ~180MB HBM.
__global__ __launch_bounds__(256, 1) void k_conv(
    const float* __restrict__ x,      // [4][64][512][512] fp32
    const ushort* __restrict__ wb,    // [4][64co][9][64ci] bf16 (swizzle baked)
    const float* __restrict__ noise,  // [4][1][512][512]
    const float* __restrict__ bias,   // [64]
    float* __restrict__ out) {        // [4][64][512][512] fp32
    extern __shared__ __align__(16) ushort lds[];

    const int t = threadIdx.x;
    const int w = t >> 6;                // wave 0..3 = row-pair
    const int lane = t & 63;
    const int n5 = lane & 31;            // MFMA N/M lane coord
    const int hl = lane >> 5;            // k-half (8 ci)
    const int blk = blockIdx.x;
    const int b = blk >> 6;
    const int band = blk & 63;
    const int ty = band * 8;

    const float* xb = x + (size_t)b * 64 * HW;
    const ushort* wA = wb + (size_t)b * 64 * 576;

    // ---- stage A once: 72 x 1KB linear copy ----
    #pragma unroll
    for (int jj = 0; jj < 18; ++jj) {
        int j = w + jj * 4;
        const ushort* src = wA + j * 512 + lane * 8;
        __builtin_amdgcn_global_load_lds(
            (const __attribute__((address_space(1))) unsigned int*)src,
            (__attribute__((address_space(3))) unsigned int*)&lds[j * 512],
            16, 0, 0);
    }

    // ---- chunk staging: 25 x 1KB gload_lds of x fp32 into F (R5-proven) ----
    auto stage_chunk = [&](int cc, int txn) {
        #pragma unroll
        for (int kk = 0; kk < 7; ++kk) {
            int k = w + kk * 4;
            if (k < 25) {
                int f = k * 256 + 4 * lane;        // dword index into F (max 6396, exact fit)
                int ci = f / 400;                  // 400 dwords per local-ci (10r x 40c)
                int rem = f - ci * 400;
                int row = rem / 40;
                int col = rem - row * 40;
                int gy = ty - 1 + row;  gy = gy < 0 ? 0 : (gy > 511 ? 511 : gy);
                int gx = txn - 4 + col; gx = gx < 0 ? 0 : (gx > 508 ? 508 : gx);
                const float* src = xb + (size_t)(cc * 16 + ci) * HW + gy * WW + gx;
                __builtin_amdgcn_global_load_lds(
                    (const __attribute__((address_space(1))) unsigned int*)src,
                    (__attribute__((address_space(3))) unsigned int*)
                        ((unsigned int*)&lds[F_OFF_U] + k * 256),
                    16, 0, 0);
            }
        }
    };

    // ---- cvt chunk cc: F fp32 -> T bf16 slice (16 ci), xpose-inner (R5-proven) ----
    auto cvt_chunk = [&](int cc, int txn) {
        const float* F = (const float*)&lds[F_OFF_U];
        #pragma unroll
        for (int q = 0; q < 3; ++q) {
            int id = t + q * 256;
            if (id < 680) {                    // 10 rows x 34 lcol x 2 ci-groups
                int lcol = id % 34;
                int rem = id / 34;
                int cs = rem & 1;              // 8-ci group within chunk
                int row = rem >> 1;
                int gy = ty - 1 + row;
                int gxl = txn - 1 + lcol;
                bool ok = (gy >= 0) && (gy < HH) && (gxl >= 0) && (gxl < WW);
                int base = (8 * cs) * 400 + row * 40 + (lcol + 3);
                float v[8];
                #pragma unroll
                for (int j = 0; j < 8; ++j)
                    v[j] = ok ? F[base + j * 400] : 0.f;
                uint pk[4];
                #pragma unroll
                for (int j = 0; j < 4; ++j)
                    pk[j] = cvtpk(v[2 * j], v[2 * j + 1]);
                int grp = ((2 * cc + cs) ^ (lcol & 7)) << 3;   // swizzled 8-ci slot
                uint4* dst = (uint4*)&lds[T_OFF_U + (row * 34 + lcol) * 64 + grp];
                *dst = make_uint4(pk[0], pk[1], pk[2], pk[3]);
            }
        }
    };

    // ---- prologue: stage+convert tile0 (tx=0) ----
    for (int cc = 0; cc < 4; ++cc) {
        stage_chunk(cc, 0);
        __syncthreads();
        cvt_chunk(cc, 0);
        __syncthreads();
    }

    // ---- A read bases (R15 verbatim) ----
    int aidx[2];
    #pragma unroll
    for (int mt = 0; mt < 2; ++mt)
        aidx[mt] = (mt * 32 + n5) * 576 + ((hl ^ (n5 & 7)) << 3);

    // ---- B read bases (R15 verbatim): row = 2w + (n5>>4) ----
    int bidx[2][3];
    const int brow = 2 * w + (n5 >> 4);
    #pragma unroll
    for (int i = 0; i < 2; ++i)
        #pragma unroll
        for (int dx = 0; dx < 3; ++dx) {
            int lcol = i * 16 + (n5 & 15) + dx;
            bidx[i][dx] = (brow * 34 + lcol) * 64 + ((hl ^ (lcol & 7)) << 3);
        }

    const float* nz = noise + (size_t)b * HW;
    const int orow = ty + brow;           // output row for this lane

    for (int it = 0; it < 16; ++it) {
        const int tx = it * 32;

        // noise loads (retired by the chunk-cycle syncs before epilogue use)
        float nv[2];
        #pragma unroll
        for (int i = 0; i < 2; ++i)
            nv[i] = nz[orow * WW + tx + i * 16 + (n5 & 15)];

        // issue next tile's chunk0 (F is free; lands under MFMA)
        if (it < 15) stage_chunk(0, tx + 32);

        // ---- compute from T: 4 ds_read_b128 -> 4 MFMA(32x32x16) per phase (R15) ----
        const ushort* bufp = &lds[T_OFF_U];
        f32x16 acc[2][2];
        #pragma unroll
        for (int mt = 0; mt < 2; ++mt)
            #pragma unroll
            for (int i = 0; i < 2; ++i)
                acc[mt][i] = (f32x16){0.f,0.f,0.f,0.f,0.f,0.f,0.f,0.f,
                                      0.f,0.f,0.f,0.f,0.f,0.f,0.f,0.f};

        #pragma unroll
        for (int dy = 0; dy < 3; ++dy) {
            #pragma unroll
            for (int dx = 0; dx < 3; ++dx) {
                const int off = dy * 3 + dx;
                #pragma unroll
                for (int kb = 0; kb < 4; ++kb) {
                    bf16x8 afr[2], bfr[2];
                    #pragma unroll
                    for (int mt = 0; mt < 2; ++mt)
                        afr[mt] = *(const bf16x8*)
                            &lds[(aidx[mt] + off * 64) ^ (kb << 4)];
                    #pragma unroll
                    for (int i = 0; i < 2; ++i)
                        bfr[i] = *(const bf16x8*)
                            &bufp[(bidx[i][dx] + dy * (34 * 64)) ^ (kb << 4)];
                    #pragma unroll
                    for (int mt = 0; mt < 2; ++mt)
                        #pragma unroll
                        for (int i = 0; i < 2; ++i)
                            acc[mt][i] = __builtin_amdgcn_mfma_f32_32x32x16_bf16(
                                afr[mt], bfr[i], acc[mt][i], 0, 0, 0);
                }
            }
        }

        // ---- chunk cycle: rebuild T for tile it+1 (MFMA done reading T) ----
        if (it < 15) {
            for (int cc = 0; cc < 4; ++cc) {
                __syncthreads();               // chunk cc landed (full drain) + all waves past MFMA/cvt
                cvt_chunk(cc, tx + 32);
                __syncthreads();               // F free block-wide
                if (cc < 3) stage_chunk(cc + 1, tx + 32);
            }
        }

        // ---- epilogue (R15 verbatim, coalesced): stores fly into next MFMA ----
        // C layout (m74/m101): col = lane&31 (px), row = (reg&3)+8*(reg>>2)+4*hl (co)
        #pragma unroll
        for (int mt = 0; mt < 2; ++mt) {
            #pragma unroll
            for (int i = 0; i < 2; ++i) {
                const int ocol = tx + i * 16 + (n5 & 15);
                #pragma unroll
                for (int reg = 0; reg < 16; ++reg) {
                    int co = mt * 32 + (reg & 3) + 8 * (reg >> 2) + 4 * hl;
                    float y = acc[mt][i][reg] + nv[i] + bias[co];
                    y = (y >= 0.f ? y : 0.2f * y) * 1.41421356237f;
                    y = fminf(fmaxf(y, -256.f), 256.f);
                    out[((size_t)(b * 64 + co) * HH + orow) * WW + ocol] = y;
                }
            }
        }
    }
}

extern "C" void kernel_launch(void* const* d_in, const int* in_sizes, int n_in,
                              void* d_out, int out_size, void* d_ws, size_t ws_size,
                              hipStream_t stream) {
    const float* x     = (const float*)d_in[0];
    const float* wsv   = (const float*)d_in[1];
    const float* noise = (const float*)d_in[2];
    const float* aw    = (const float*)d_in[3];
    const float* ab    = (const float*)d_in[4];
    const float* cw    = (const float*)d_in[5];
    const float* bias  = (const float*)d_in[6];
    float* out = (float*)d_out;

    float*  styles = (float*)d_ws;                          // 1 KB
    ushort* wb16   = (ushort*)((char*)d_ws + 1024);         // 294912 B

    hipFuncSetAttribute((const void*)k_conv,
                        hipFuncAttributeMaxDynamicSharedMemorySize, LDS_BYTES);

    k_styles<<<256, 64, 0, stream>>>(wsv, aw, ab, styles);
    k_wmod<<<256, 64, 0, stream>>>(cw, styles, wb16);
    k_conv<<<256, 256, LDS_BYTES, stream>>>(x, wb16, noise, bias, out);
}

// Round 19
// 220.098 us; speedup vs baseline: 1.2496x; 1.2496x over previous
//
#include <hip/hip_runtime.h>
#include <math.h>

#define HH 512
#define WW 512
#define HW (HH * WW)
#define PW 514                    // padded width/height
#define PPIX (PW * PW)

#define A_U 36864                 // 64co*9off*64ci ushorts = 73728 B
#define B_U 22016                 // 43 loads x 512 ushorts = 44032 B per B buffer
#define LDS_BYTES ((A_U + 2 * B_U) * 2)   // 161792 B <= 160 KiB pool

typedef short bf16x8 __attribute__((ext_vector_type(8)));
typedef float f32x4  __attribute__((ext_vector_type(4)));
typedef float f32x16 __attribute__((ext_vector_type(16)));

__device__ __forceinline__ ushort f2bf(float f) {
    union { float f; uint u; } c; c.f = f;
    uint u = c.u;
    return (ushort)((u + 0x7fffu + ((u >> 16) & 1u)) >> 16);
}

__device__ __forceinline__ uint cvtpk(float a, float b) {
    uint r;
    asm("v_cvt_pk_bf16_f32 %0, %1, %2" : "=v"(r) : "v"(a), "v"(b));
    return r;
}

// ---------------- kernel 1: styles ----------------
__global__ void k_styles(const float* __restrict__ wsv, const float* __restrict__ aw,
                         const float* __restrict__ ab, float* __restrict__ styles) {
    int bid = blockIdx.x;
    int b = bid >> 6, ci = bid & 63;
    int l = threadIdx.x;
    const float* wrow = wsv + b * 512;
    const float* arow = aw + ci * 512;
    float s = 0.f;
    #pragma unroll
    for (int j = 0; j < 8; ++j)
        s += wrow[l + 64 * j] * arow[l + 64 * j];
    #pragma unroll
    for (int off = 32; off; off >>= 1)
        s += __shfl_xor(s, off, 64);
    if (l == 0)
        styles[b * 64 + ci] = s * 0.044194173824159216f + ab[ci];
}

// ------------- kernel 2: modulate+demodulate -> bf16 [b][co][off 9][ci 64] -------------
// ci-group (ci>>3) stored XORed with (co&7): conflict-free weight ds_reads after a
// purely LINEAR global_load_lds stage (swizzle baked at write time). (R8/R10-proven)
__global__ void k_wmod(const float* __restrict__ cw, const float* __restrict__ styles,
                       ushort* __restrict__ wb) {
    int b = blockIdx.x >> 6, co = blockIdx.x & 63;
    int ci = threadIdx.x;
    float st = styles[b * 64 + ci];
    const float* wp = cw + (co * 64 + ci) * 9;
    float wv[9];
    float ss = 0.f;
    #pragma unroll
    for (int k = 0; k < 9; ++k) { wv[k] = wp[k] * st; ss += wv[k] * wv[k]; }
    #pragma unroll
    for (int off = 32; off; off >>= 1)
        ss += __shfl_xor(ss, off, 64);
    float dm = 1.0f / sqrtf(ss + 1e-8f);
    int cisw = ((((ci >> 3) ^ co) & 7) << 3) | (ci & 7);
    #pragma unroll
    for (int k = 0; k < 9; ++k)
        wb[((size_t)(b * 64 + co) * 9 + k) * 64 + cisw] = f2bf(wv[k] * dm);
}

// ------------- kernel 2c: x fp32 NCHW -> xp bf16 [b][gy+1][gx+1][ci], pad fused -------------
__global__ __launch_bounds__(256) void k_xpose(
    const float* __restrict__ x, ushort* __restrict__ xp) {
    const int t = threadIdx.x;
    const int bid = blockIdx.x;

    if (bid >= 8192) {            // ---- fused zeropad of the border ----
        int id = (bid - 8192) * 256 + t;
        if (id >= 4 * 2052) return;
        int b = id / 2052, r = id % 2052;
        int gyp, gxp;
        if (r < 514)       { gyp = 0;        gxp = r; }
        else if (r < 1028) { gyp = 513;      gxp = r - 514; }
        else if (r < 1540) { gyp = r - 1027; gxp = 0; }
        else               { gyp = r - 1539; gxp = 513; }
        ushort* p = xp + (((size_t)b * PW + gyp) * PW + gxp) * 64;
        uint4 z = make_uint4(0, 0, 0, 0);
        #pragma unroll
        for (int i = 0; i < 8; ++i) *(uint4*)(p + i * 8) = z;
        return;
    }

    __shared__ ushort lt[128 * 68];
    const int gxt = bid & 3;
    const int gy  = (bid >> 2) & 511;
    const int b   = bid >> 11;

    const float* xb = x + (size_t)b * 64 * HW + (size_t)gy * WW + gxt * 128;
    const int ci0 = 8 * (t >> 5);
    const int gxc = t & 31;

    f32x4 v[8];
    #pragma unroll
    for (int j = 0; j < 8; ++j)
        v[j] = *(const f32x4*)(xb + (size_t)(ci0 + j) * HW + gxc * 4);

    #pragma unroll
    for (int p = 0; p < 4; ++p) {
        int px = gxc * 4 + p;
        int rowp = ((px & 3) * 32 + (px >> 2)) * 68;
        #pragma unroll
        for (int cg = 0; cg < 2; ++cg) {
            uint lo = cvtpk(v[4 * cg + 0][p], v[4 * cg + 1][p]);
            uint hi = cvtpk(v[4 * cg + 2][p], v[4 * cg + 3][p]);
            *(uint2*)&lt[rowp + ci0 + 4 * cg] = make_uint2(lo, hi);
        }
    }
    __syncthreads();

    const int px = t >> 1, half = t & 1;
    const int rowp = ((px & 3) * 32 + (px >> 2)) * 68 + half * 32;
    uint4 o0 = *(uint4*)&lt[rowp + 0];
    uint4 o1 = *(uint4*)&lt[rowp + 8];
    uint4 o2 = *(uint4*)&lt[rowp + 16];
    uint4 o3 = *(uint4*)&lt[rowp + 24];
    ushort* dst = xp + (((size_t)b * PW + (gy + 1)) * PW + (gxt * 128 + px + 1)) * 64
                     + half * 32;
    *(uint4*)(dst + 0)  = o0;
    *(uint4*)(dst + 8)  = o1;
    *(uint4*)(dst + 16) = o2;
    *(uint4*)(dst + 24) = o3;
}

// ------------- kernel 3: persistent 4-wave MFMA conv, 32x32x16, A-in-LDS, B dbuf -------------
// R19 = R15 (session best, 231.8us) + T1 XCD-aware band swizzle:
// XCD = blockIdx%8 (HW round-robin). band = (j&7)*8 + (j>>3) gives each XCD
// 8 CONSECUTIVE bands per image -> adjacent bands' shared halo rows of xp and
// the per-image A-weights (288KB) become L2-local instead of cross-XCD.
// Pipeline (R15): noise -> STAGE_ISSUE(next) -> compute -> stores -> vmcnt(63)
// [retire noise+stage+1; stores stay in flight] -> raw s_barrier.
__global__ __launch_bounds__(256, 1) void k_conv(
    const ushort* __restrict__ xp,    // [4][514][514][64] bf16 padded
    const ushort* __restrict__ wb,    // [4][64co][9][64ci] bf16 (swizzle baked)
    const float* __restrict__ noise,  // [4][1][512][512]
    const float* __restrict__ bias,   // [64]
    float* __restrict__ out) {        // [4][64][512][512] fp32
    extern __shared__ __align__(16) ushort lds[];

    const int t = threadIdx.x;
    const int w = t >> 6;                // wave 0..3 = row-pair
    const int lane = t & 63;
    const int n5 = lane & 31;            // MFMA N/M lane coord
    const int hl = lane >> 5;            // k-half (8 ci)
    const int blk = blockIdx.x;
    const int b = blk >> 6;
    const int j64 = blk & 63;
    const int band = (j64 & 7) * 8 + (j64 >> 3);   // T1: XCD j64&7 owns bands 8k..8k+7
    const int ty = band * 8;

    const ushort* xpb = xp + (size_t)b * PPIX * 64;
    const ushort* wA  = wb + (size_t)b * 64 * 576;

    // ---- stage A once: 72 x 1KB linear copy ----
    #pragma unroll
    for (int jj = 0; jj < 18; ++jj) {
        int j = w + jj * 4;
        const ushort* src = wA + j * 512 + lane * 8;
        __builtin_amdgcn_global_load_lds(
            (const __attribute__((address_space(1))) unsigned int*)src,
            (__attribute__((address_space(3))) unsigned int*)&lds[j * 512],
            16, 0, 0);
    }

    // ---- B staging source offsets (tile-invariant) ----
    int soff[11];
    #pragma unroll
    for (int jj = 0; jj < 11; ++jj) {
        int j = w + jj * 4;
        if (j < 43) {
            int c = j * 64 + lane;
            int c2 = c < 2719 ? c : 2719;  // tail clamp (src only; dst stays linear)
            int cig = c2 & 7;
            int pxl = c2 >> 3;
            int row = pxl / 34;
            int lcol = pxl - row * 34;
            int gsrc = cig ^ (lcol & 7);   // pre-swizzled source ci-group (R8-proven)
            soff[jj] = ((ty + row) * PW + lcol) * 64 + gsrc * 8;
        } else soff[jj] = 0;
    }

    // ---- prologue: stage tile0 (tx=0) into buf0 ----
    #pragma unroll
    for (int jj = 0; jj < 11; ++jj) {
        int j = w + jj * 4;
        if (j < 43)
            __builtin_amdgcn_global_load_lds(
                (const __attribute__((address_space(1))) unsigned int*)(xpb + soff[jj]),
                (__attribute__((address_space(3))) unsigned int*)&lds[A_U + j * 512],
                16, 0, 0);
    }
    asm volatile("s_waitcnt vmcnt(0)" ::: "memory");
    __syncthreads();

    // ---- A read bases ----
    int aidx[2];
    #pragma unroll
    for (int mt = 0; mt < 2; ++mt)
        aidx[mt] = (mt * 32 + n5) * 576 + ((hl ^ (n5 & 7)) << 3);

    // ---- B read bases: row = 2w + (n5>>4), col = i*16 + (n5&15) + dx ----
    int bidx[2][3];
    const int brow = 2 * w + (n5 >> 4);
    #pragma unroll
    for (int i = 0; i < 2; ++i)
        #pragma unroll
        for (int dx = 0; dx < 3; ++dx) {
            int lcol = i * 16 + (n5 & 15) + dx;
            bidx[i][dx] = (brow * 34 + lcol) * 64 + ((hl ^ (lcol & 7)) << 3);
        }

    const float* nz = noise + (size_t)b * HW;
    const int orow = ty + brow;           // output row for this lane

    int p = 0;
    for (int it = 0; it < 16; ++it) {
        const int tx = it * 32;

        // noise loads (oldest vmem of this iter)
        float nv[2];
        #pragma unroll
        for (int i = 0; i < 2; ++i)
            nv[i] = nz[orow * WW + tx + i * 16 + (n5 & 15)];

        // issue next tile's staging FIRST (T3): hides under the whole compute
        if (it < 15) {
            #pragma unroll
            for (int jj = 0; jj < 11; ++jj) {
                int j = w + jj * 4;
                if (j < 43)
                    __builtin_amdgcn_global_load_lds(
                        (const __attribute__((address_space(1))) unsigned int*)
                            (xpb + soff[jj] + (tx + 32) * 64),
                        (__attribute__((address_space(3))) unsigned int*)
                            &lds[A_U + (p ^ 1) * B_U + j * 512],
                        16, 0, 0);
            }
        }

        // ---- compute from buf p: 4 ds_read_b128 -> 4 MFMA(32x32x16) per phase ----
        const ushort* bufp = &lds[A_U + p * B_U];
        f32x16 acc[2][2];
        #pragma unroll
        for (int mt = 0; mt < 2; ++mt)
            #pragma unroll
            for (int i = 0; i < 2; ++i)
                acc[mt][i] = (f32x16){0.f,0.f,0.f,0.f,0.f,0.f,0.f,0.f,
                                      0.f,0.f,0.f,0.f,0.f,0.f,0.f,0.f};

        #pragma unroll
        for (int dy = 0; dy < 3; ++dy) {
            #pragma unroll
            for (int dx = 0; dx < 3; ++dx) {
                const int off = dy * 3 + dx;
                #pragma unroll
                for (int kb = 0; kb < 4; ++kb) {
                    bf16x8 afr[2], bfr[2];
                    #pragma unroll
                    for (int mt = 0; mt < 2; ++mt)
                        afr[mt] = *(const bf16x8*)
                            &lds[(aidx[mt] + off * 64) ^ (kb << 4)];
                    #pragma unroll
                    for (int i = 0; i < 2; ++i)
                        bfr[i] = *(const bf16x8*)
                            &bufp[(bidx[i][dx] + dy * (34 * 64)) ^ (kb << 4)];
                    #pragma unroll
                    for (int mt = 0; mt < 2; ++mt)
                        #pragma unroll
                        for (int i = 0; i < 2; ++i)
                            acc[mt][i] = __builtin_amdgcn_mfma_f32_32x32x16_bf16(
                                afr[mt], bfr[i], acc[mt][i], 0, 0, 0);
                }
            }
        }

        // ---- epilogue: +noise, +bias, lrelu*sqrt2, clamp, store (stores youngest) ----
        // C layout (m74/m101): col = lane&31 (px), row = (reg&3)+8*(reg>>2)+4*hl (co)
        #pragma unroll
        for (int mt = 0; mt < 2; ++mt) {
            #pragma unroll
            for (int i = 0; i < 2; ++i) {
                const int ocol = tx + i * 16 + (n5 & 15);
                #pragma unroll
                for (int reg = 0; reg < 16; ++reg) {
                    int co = mt * 32 + (reg & 3) + 8 * (reg >> 2) + 4 * hl;
                    float y = acc[mt][i][reg] + nv[i] + bias[co];
                    y = (y >= 0.f ? y : 0.2f * y) * 1.41421356237f;
                    y = fminf(fmaxf(y, -256.f), 256.f);
                    out[((size_t)(b * 64 + co) * HH + orow) * WW + ocol] = y;
                }
            }
        }

        // counted drain (T4): retire noise+stage (oldest 14); leave stores in flight
        asm volatile("s_waitcnt vmcnt(63)" ::: "memory");
        __builtin_amdgcn_sched_barrier(0);
        __builtin_amdgcn_s_barrier();
        p ^= 1;
    }
}

extern "C" void kernel_launch(void* const* d_in, const int* in_sizes, int n_in,
                              void* d_out, int out_size, void* d_ws, size_t ws_size,
                              hipStream_t stream) {
    const float* x     = (const float*)d_in[0];
    const float* wsv   = (const float*)d_in[1];
    const float* noise = (const float*)d_in[2];
    const float* aw    = (const float*)d_in[3];
    const float* ab    = (const float*)d_in[4];
    const float* cw    = (const float*)d_in[5];
    const float* bias  = (const float*)d_in[6];
    float* out = (float*)d_out;

    float*  styles = (float*)d_ws;                          // 1 KB
    ushort* wb16   = (ushort*)((char*)d_ws + 1024);         // 294912 B
    ushort* xpad   = (ushort*)((char*)d_ws + (1 << 20));    // 135.3 MB

    hipFuncSetAttribute((const void*)k_conv,
                        hipFuncAttributeMaxDynamicSharedMemorySize, LDS_BYTES);

    k_styles<<<256, 64, 0, stream>>>(wsv, aw, ab, styles);
    k_wmod<<<256, 64, 0, stream>>>(cw, styles, wb16);
    k_xpose<<<8225, 256, 0, stream>>>(x, xpad);
    k_conv<<<256, 256, LDS_BYTES, stream>>>(xpad, wb16, noise, bias, out);
}